// Round 21
// baseline (3919.054 us; speedup 1.0000x reference)
//
#include <hip/hip_runtime.h>
#include <hip/hip_bf16.h>

#define NROW 8192
#define NDIM 256
#define INV_T (1.0f / 0.07f)
#define K_BOT 819      // first selected descending rank
#define K_TOP 4095     // one past last selected rank
#define N_SEL 3276
#define N_UNSEL 4916   // 8192 - N_SEL (includes diagonal at -10)
#define K16 0xC180u    // key of value 16.0 (binade [16,32) = 128 keys)
#define K32 0xC200u    // key of value 32.0

typedef unsigned int u32;
typedef unsigned short u16;
typedef unsigned char u8;
typedef short s16;
typedef unsigned long long u64;
typedef __bf16 bf16_t;
typedef s16 s16x8 __attribute__((ext_vector_type(8)));
typedef float f32x4 __attribute__((ext_vector_type(4)));

__device__ __forceinline__ u16 bfbits(float f) {
    return __builtin_bit_cast(u16, (bf16_t)f);   // RNE f32->bf16, raw bits
}
__device__ __forceinline__ u16 map16(u16 b) {
    return (b & 0x8000u) ? (u16)~b : (u16)(b | 0x8000u);
}
__device__ __forceinline__ float unmap16(u32 m) {
    u16 b = (m & 0x8000u) ? (u16)(m & 0x7FFFu) : (u16)~(u16)m;
    return __uint_as_float(((u32)b) << 16);
}
__device__ __forceinline__ float bf2f(s16 v) {
    return __uint_as_float(((u32)(u16)v) << 16);
}

__device__ __forceinline__ void gload16(const void* g, void* l) {
    __builtin_amdgcn_global_load_lds(
        (const __attribute__((address_space(1))) u32*)g,
        (__attribute__((address_space(3))) u32*)l, 16, 0, 0);
}

__device__ __forceinline__ u32 wave_sum_u32(u32 x) {
#pragma unroll
    for (int o = 32; o; o >>= 1) x += __shfl_down(x, o);
    return __shfl(x, 0);
}

// resolve rank `rem` within a 128-key sub-hist (packed u16 counts, 64 words)
__device__ __forceinline__ void resolve_slot(const u32* sub, u32 rem,
                                             int lane, u32* idxOut, u32* gtOut) {
    u32 word = sub[lane];
    u32 c0 = word & 0xFFFFu, c1 = word >> 16;     // d = 2*lane, 2*lane+1
    u32 s0 = c0 + c1, suf = s0;
#pragma unroll
    for (int o = 1; o < 64; o <<= 1) {
        u32 v = __shfl_down(suf, o);
        if (lane + o < 64) suf += v;
    }
    u32 TexL = suf - s0;                  // counts in higher lanes (bigger keys)
    u32 f = 0, pk = 0;
    u32 ab0 = TexL + c1;
    if (rem >= ab0 && rem < ab0 + c0) { f = 1; pk = ((u32)(lane * 2) << 16) | ab0; }
    if (rem >= TexL && rem < TexL + c1) { f = 1; pk = ((u32)(lane * 2 + 1) << 16) | TexL; }
    u64 mm = __ballot(f != 0);
    pk = __shfl(pk, (int)(__ffsll((unsigned long long)mm) - 1));
    *idxOut = pk >> 16;
    *gtOut = pk & 0xFFFFu;
}

// ---------------- fp32 -> bf16 (both inputs, one launch) ----------------
__global__ __launch_bounds__(256) void cvt_bf16(const float* __restrict__ in0,
                                                const float* __restrict__ in1,
                                                u16* __restrict__ out0,
                                                u16* __restrict__ out1) {
    int b = blockIdx.x;
    const float* in = (b < 2048) ? in0 : in1;
    u16* out = (b < 2048) ? out0 : out1;
    int i = ((b & 2047) * 256 + threadIdx.x) * 4;
    float4 v = *(const float4*)(in + i);
    ushort4 o;
    o.x = bfbits(v.x); o.y = bfbits(v.y); o.z = bfbits(v.z); o.w = bfbits(v.w);
    *(ushort4*)(out + i) = o;
}

// ---------------- GEMM -> u8 rank codes ----------------
// Proven round-14 GEMM core (128x128, BK=64, 8 waves, wave 64x32). Epilogue
// writes u8 code per key: 0 = value<16, 255 = value>=32, else 1+d where
// d = key - key(16.0) in [0,128) — exact within the binade [16,32).
__global__ __launch_bounds__(512) void gemm_codes(const u16* __restrict__ Qb,
                                                  const u16* __restrict__ Kb,
                                                  u8* __restrict__ Cp8) {
    constexpr int BK = 64;
    __shared__ __align__(16) char smem[32768];
    u16* sA = (u16*)smem;                    // [128][64] bf16 (16 KB)
    u16* sB = (u16*)(smem + 16384);          // [128][64] (16 KB)
    u8*  sC8 = (u8*)smem;                    // [128][144] epilogue (18.0 KB)

    const int tid  = threadIdx.x;
    const int lane = tid & 63;
    const int wid  = tid >> 6;               // 0..7
    const int wr = wid & 1;
    const int wc = wid >> 1;
    const int r0 = blockIdx.y * 128;
    const int bn = blockIdx.x * 128;
    const int kg = lane >> 4;
    const int fr = lane & 15;
    const int srr = lane >> 3;
    const int srj = (lane & 7) ^ srr;

    f32x4 acc[4][2] = {};

    for (int k0 = 0; k0 < NDIM; k0 += BK) {
        __syncthreads();
#pragma unroll
        for (int s = 0; s < 2; ++s) {
            int seg = wid * 2 + s;
            int row = seg * 8 + srr;
            gload16(Qb + (size_t)(r0 + row) * NDIM + k0 + srj * 8, &sA[seg * 512]);
            gload16(Kb + (size_t)(bn + row) * NDIM + k0 + srj * 8, &sB[seg * 512]);
        }
        __syncthreads();

#pragma unroll
        for (int kk = 0; kk < 2; ++kk) {
            s16x8 af[4], bfv[2];
            const int jp = (kk * 4 + kg) ^ (fr & 7);
#pragma unroll
            for (int m = 0; m < 4; ++m) {
                int row = wr * 64 + m * 16 + fr;
                af[m] = *(const s16x8*)(&sA[row * BK + jp * 8]);
            }
#pragma unroll
            for (int n = 0; n < 2; ++n) {
                int row = wc * 32 + n * 16 + fr;
                bfv[n] = *(const s16x8*)(&sB[row * BK + jp * 8]);
            }
#pragma unroll
            for (int m = 0; m < 4; ++m)
#pragma unroll
                for (int n = 0; n < 2; ++n)
                    acc[m][n] = __builtin_amdgcn_mfma_f32_16x16x32_bf16(
                        af[m], bfv[n], acc[m][n], 0, 0, 0);
        }
    }

    __syncthreads();   // done reading sA/sB; reuse LDS as sC8
#pragma unroll
    for (int m = 0; m < 4; ++m)
#pragma unroll
        for (int n = 0; n < 2; ++n)
#pragma unroll
            for (int jj = 0; jj < 4; ++jj) {
                int r = wr * 64 + m * 16 + kg * 4 + jj;   // C/D: row=(lane>>4)*4+reg
                int c = wc * 32 + n * 16 + fr;            //      col=lane&15
                u32 key = (u32)map16(bfbits(acc[m][n][jj]));
                u32 d = key - K16;
                u32 code = (key >= K32) ? 255u : ((d < 128u) ? (d + 1u) : 0u);
                bool dz = (r0 + r == bn + c);             // diagonal excluded
                sC8[r * 144 + c] = (u8)(dz ? 0u : code);
            }
    __syncthreads();
#pragma unroll
    for (int it = 0; it < 2; ++it) {
        int idx = it * 512 + tid;                 // 1024 chunks of 16B
        int row = idx >> 3, col16 = (idx & 7) * 16;
        *(uint4*)(Cp8 + (size_t)(r0 + row) * NROW + bn + col16) =
            *(const uint4*)(&sC8[row * 144 + col16]);
    }
}

// ---------------- rank select + LSE on u8 codes: 1 wave/row, one sweep ----
__global__ __launch_bounds__(128) void rank_lse8(const u8* __restrict__ Cp8,
                                                 const float* __restrict__ fq,
                                                 const float* __restrict__ fk,
                                                 float* __restrict__ loss,
                                                 u32* __restrict__ flags) {
    __shared__ u32 subs[2][64];           // 512 B/block; per-wave private
    const int t = threadIdx.x;
    const int w = t >> 6;
    const int lane = t & 63;
    const int row = blockIdx.x * 2 + w;

    u32* sub = subs[w];
    sub[lane] = 0;                        // wave-private zero (DS in-order)

    const uint4* rp8 = (const uint4*)(Cp8 + (size_t)row * NROW);

    // exact fp32 l_pos
    float lp;
    {
        float4 q4 = *(const float4*)(fq + (size_t)row * NDIM + lane * 4);
        float4 k4 = *(const float4*)(fk + (size_t)row * NDIM + lane * 4);
        float p = q4.x * k4.x + q4.y * k4.y + q4.z * k4.z + q4.w * k4.w;
#pragma unroll
        for (int o = 32; o; o >>= 1) p += __shfl_down(p, o);
        lp = __shfl(p, 0);
    }

    // ---- single sweep over 8192 codes (8 x uint4 per lane) ----
    u32 cntHi = 0;
#pragma unroll 4
    for (int i = 0; i < 8; ++i) {
        uint4 v = rp8[i * 64 + lane];
        u32 ww[4] = { v.x, v.y, v.z, v.w };
#pragma unroll
        for (int q = 0; q < 4; ++q) {
#pragma unroll
            for (int bi = 0; bi < 4; ++bi) {
                u32 c = (ww[q] >> (bi * 8)) & 255u;
                cntHi += (c == 255u) ? 1u : 0u;
                u32 d = c - 1u;                 // [0,128) iff code in [1,128]
                if (d < 128u)
                    atomicAdd(&sub[d >> 1], (d & 1u) ? 0x10000u : 1u);
            }
        }
    }
    const u32 CH = wave_sum_u32(cntHi);

    // R-range total
    u32 NR;
    {
        u32 wv = sub[lane];
        NR = wave_sum_u32((wv & 0xFFFFu) + (wv >> 16));
    }

    bool fb = !((CH <= (u32)K_BOT) && ((u32)K_BOT < CH + NR))
            || ((u32)(K_TOP - 1) < CH + NR);

    u32 ua = 0, Ga = 0, Ea = 0;
    float a = 0.f;
    if (!fb) {
        const u32 remA = (u32)K_BOT - CH;
        u32 idxA, gtA;
        resolve_slot(sub, remA, lane, &idxA, &gtA);
        ua = K16 + idxA;
        Ga = CH + gtA;
        {
            u32 wv = sub[idxA >> 1];
            Ea = (idxA & 1u) ? (wv >> 16) : (wv & 0xFFFFu);
        }
        a = unmap16(ua);
        if (!(a >= 18.9f)) fb = true;   // dropped sub-16 terms < e^-41 need a>=18.8
    }

    if (!fb) {
        const float m_ = fmaxf(fmaxf(lp, a), -10.0f) * INV_T;
        float sm = 0.f;
        {
            u32 wv = sub[lane];
            u32 c0 = wv & 0xFFFFu, c1 = wv >> 16;
            u32 k0 = K16 + (u32)(lane * 2);
            u32 k1 = k0 | 1u;
            if (c0 && k0 < ua) sm += (float)c0 * __expf(unmap16(k0) * INV_T - m_);
            if (c1 && k1 < ua) sm += (float)c1 * __expf(unmap16(k1) * INV_T - m_);
        }
#pragma unroll
        for (int o = 32; o; o >>= 1) sm += __shfl_down(sm, o);
        if (lane == 0) {
            float expA = __expf(a * INV_T - m_);
            float tot = sm + (float)(int)(Ga + Ea - (u32)K_BOT) * expA;
            // terms below value 16 (incl. B-side): < 1e-14 relative, omitted
            tot += __expf(lp * INV_T - m_)
                 + (float)N_UNSEL * __expf(-10.0f * INV_T - m_);
            loss[row] = m_ + __logf(tot) - lp * INV_T;
            flags[row] = 0u;
        }
    } else {
        if (lane == 0) flags[row] = 1u;   // fixup recomputes exactly
    }
}

// ---------------- fixup: exact recompute for flagged rows (rare) ----------
__global__ __launch_bounds__(256) void fixup(const u16* __restrict__ Qb,
                                             const u16* __restrict__ Kb,
                                             const float* __restrict__ fq,
                                             const float* __restrict__ fk,
                                             const u32* __restrict__ flags,
                                             float* __restrict__ loss) {
    __shared__ u16 skey[4][NROW];   // 64 KB (per-wave row buffer)
    const int wid = threadIdx.x >> 6, lane = threadIdx.x & 63;
    const int gw = blockIdx.x * 4 + wid;    // 0..255

    for (int rr = 0; rr < 32; ++rr) {
        const int row = gw * 32 + rr;
        if (!flags[row]) continue;
        u16* K = skey[wid];
        for (int j = 0; j < 128; ++j) {
            int c = j * 64 + lane;
            float dot = 0.f;
            for (int kc = 0; kc < 32; ++kc) {
                s16x8 qv = *(const s16x8*)(Qb + (size_t)row * NDIM + kc * 8);
                s16x8 kv = *(const s16x8*)(Kb + (size_t)c * NDIM + kc * 8);
#pragma unroll
                for (int e = 0; e < 8; ++e) dot += bf2f(qv[e]) * bf2f(kv[e]);
            }
            K[c] = (c == row) ? (u16)0 : map16(bfbits(dot));
        }
        auto cntAbove = [&](u32 mid) {
            u32 pc = 0;
            for (int i = 0; i < 128; ++i) pc += (u32)(K[i * 64 + lane] > mid);
            return wave_sum_u32(pc);
        };
        u32 lo = 0, hi = 65535;
        while (lo < hi) { u32 mid = (lo + hi) >> 1;
            if (cntAbove(mid) <= (u32)K_BOT) hi = mid; else lo = mid + 1; }
        const u32 ua = lo;
        lo = 0; hi = 65535;
        while (lo < hi) { u32 mid = (lo + hi) >> 1;
            if (cntAbove(mid) <= (u32)(K_TOP - 1)) hi = mid; else lo = mid + 1; }
        const u32 ub = lo;
        float lp;
        {
            float4 q4 = *(const float4*)(fq + (size_t)row * NDIM + lane * 4);
            float4 k4 = *(const float4*)(fk + (size_t)row * NDIM + lane * 4);
            float p = q4.x * k4.x + q4.y * k4.y + q4.z * k4.z + q4.w * k4.w;
#pragma unroll
            for (int o = 32; o; o >>= 1) p += __shfl_down(p, o);
            lp = __shfl(p, 0);
        }
        const float a = unmap16(ua);
        const float m_ = fmaxf(fmaxf(lp, a), -10.0f) * INV_T;
        u32 cga = 0, cea = 0, cgb = 0;
        float sm = 0.f;
        for (int i = 0; i < 128; ++i) {
            u32 u = K[i * 64 + lane];
            cga += (u > ua); cea += (u == ua); cgb += (u > ub);
            if (u > ub && u < ua) sm += __expf(unmap16(u) * INV_T - m_);
        }
        u32 Ga = wave_sum_u32(cga), Ea = wave_sum_u32(cea), Gb = wave_sum_u32(cgb);
#pragma unroll
        for (int o = 32; o; o >>= 1) sm += __shfl_down(sm, o);
        if (lane == 0) {
            float bv = unmap16(ub);
            float expA = __expf(a * INV_T - m_);
            float tot;
            if (ua == ub) {
                tot = (float)N_SEL * expA;
            } else {
                float expB = __expf(bv * INV_T - m_);
                tot = sm + (float)(int)(Ga + Ea - (u32)K_BOT) * expA
                         + (float)(int)((u32)K_TOP - Gb) * expB;
            }
            tot += __expf(lp * INV_T - m_)
                 + (float)N_UNSEL * __expf(-10.0f * INV_T - m_);
            loss[row] = m_ + __logf(tot) - lp * INV_T;
        }
    }
}

// ---------------- host ----------------
extern "C" void kernel_launch(void* const* d_in, const int* in_sizes, int n_in,
                              void* d_out, int out_size, void* d_ws, size_t ws_size,
                              hipStream_t stream) {
    const float* fq = (const float*)d_in[0];
    const float* fk = (const float*)d_in[1];
    float* out = (float*)d_out;

    char* ws = (char*)d_ws;
    u8* codes = (u8*)ws;                                   // 64 MiB
    u16* qb = (u16*)(ws + (size_t)NROW * NROW);            // 4 MiB
    u16* kb = qb + (size_t)NROW * NDIM;                    // 4 MiB
    u32* flags = (u32*)(ws + (size_t)NROW * NROW + 2 * (size_t)NROW * NDIM * 2);

    cvt_bf16<<<4096, 256, 0, stream>>>(fq, fk, qb, kb);
    gemm_codes<<<dim3(NROW / 128, NROW / 128), 512, 0, stream>>>(qb, kb, codes);
    rank_lse8<<<NROW / 2, 128, 0, stream>>>(codes, fq, fk, out, flags);
    fixup<<<64, 256, 0, stream>>>(qb, kb, fq, fk, flags, out);
}

// Round 22
// 96.124 us; speedup vs baseline: 40.7706x; 40.7706x over previous
//
#include <hip/hip_runtime.h>
#include <hip/hip_bf16.h>

#define NROW 8192
#define NDIM 256
#define INV_T (1.0f / 0.07f)
#define K_BOT 819      // first selected descending rank
#define K_TOP 4095     // one past last selected rank
#define N_SEL 3276
#define N_UNSEL 4916   // 8192 - N_SEL (includes diagonal at -10)

typedef unsigned int u32;
typedef unsigned short u16;
typedef short s16;
typedef unsigned long long u64;
typedef __bf16 bf16_t;
typedef s16 s16x8 __attribute__((ext_vector_type(8)));
typedef float f32x4 __attribute__((ext_vector_type(4)));

__device__ __forceinline__ u16 bfbits(float f) {
    return __builtin_bit_cast(u16, (bf16_t)f);   // RNE f32->bf16, raw bits
}
// order-preserving bf16-bits -> u16 key (bigger float <=> bigger key)
__device__ __forceinline__ u16 map16(u16 b) {
    return (b & 0x8000u) ? (u16)~b : (u16)(b | 0x8000u);
}
__device__ __forceinline__ float unmap16(u32 m) {
    u16 b = (m & 0x8000u) ? (u16)(m & 0x7FFFu) : (u16)~(u16)m;
    return __uint_as_float(((u32)b) << 16);
}

__device__ __forceinline__ void gload16(const void* g, void* l) {
    __builtin_amdgcn_global_load_lds(
        (const __attribute__((address_space(1))) u32*)g,
        (__attribute__((address_space(3))) u32*)l, 16, 0, 0);
}

// ---------------- fp32 -> bf16 (both inputs, one launch) ----------------
__global__ __launch_bounds__(256) void cvt_bf16(const float* __restrict__ in0,
                                                const float* __restrict__ in1,
                                                u16* __restrict__ out0,
                                                u16* __restrict__ out1) {
    int b = blockIdx.x;
    const float* in = (b < 2048) ? in0 : in1;
    u16* out = (b < 2048) ? out0 : out1;
    int i = ((b & 2047) * 256 + threadIdx.x) * 4;
    float4 v = *(const float4*)(in + i);
    ushort4 o;
    o.x = bfbits(v.x); o.y = bfbits(v.y); o.z = bfbits(v.z); o.w = bfbits(v.w);
    *(ushort4*)(out + i) = o;
}

// ---------------- GEMM: keys = map16(bf16(Q @ K^T)) ----------------
// 128x128 tile, BK=64, 8 waves (512 thr), wave tile 64x32 (acc 32 regs).
// Proven round-14 form. No min-waves launch_bounds (round-13 spill lesson).
__global__ __launch_bounds__(512) void gemm_keys(const u16* __restrict__ Qb,
                                                 const u16* __restrict__ Kb,
                                                 u16* __restrict__ Cp) {
    constexpr int BK = 64;
    __shared__ __align__(16) char smem[128 * 132 * 2];   // 33792 B (union)
    u16* sA = (u16*)smem;                    // [128][64] bf16 (16 KB)
    u16* sB = (u16*)(smem + 128 * BK * 2);   // [128][64] (16 KB)
    u16* sC = (u16*)smem;                    // [128][132] epilogue transpose

    const int tid  = threadIdx.x;
    const int lane = tid & 63;
    const int wid  = tid >> 6;               // 0..7
    const int wr = wid & 1;                  // row half   (64 rows)
    const int wc = wid >> 1;                 // col quarter (32 cols)
    const int bm = blockIdx.y * 128;
    const int bn = blockIdx.x * 128;
    const int kg = lane >> 4;
    const int fr = lane & 15;

    // staging: segment = 8 rows x 128B; lane l -> row seg*8 + (l>>3),
    // LDS chunk jp = l&7 holds source chunk j = jp ^ (row&7).
    const int srr = lane >> 3;
    const int srj = (lane & 7) ^ srr;

    f32x4 acc[4][2] = {};

    for (int k0 = 0; k0 < NDIM; k0 += BK) {
        __syncthreads();
#pragma unroll
        for (int s = 0; s < 2; ++s) {
            int seg = wid * 2 + s;               // 0..15
            int row = seg * 8 + srr;
            gload16(Qb + (size_t)(bm + row) * NDIM + k0 + srj * 8, &sA[seg * 512]);
            gload16(Kb + (size_t)(bn + row) * NDIM + k0 + srj * 8, &sB[seg * 512]);
        }
        __syncthreads();

#pragma unroll
        for (int kk = 0; kk < 2; ++kk) {
            s16x8 af[4], bfv[2];
            const int jp = (kk * 4 + kg) ^ (fr & 7);   // row&7 == fr&7 below
#pragma unroll
            for (int m = 0; m < 4; ++m) {
                int row = wr * 64 + m * 16 + fr;
                af[m] = *(const s16x8*)(&sA[row * BK + jp * 8]);
            }
#pragma unroll
            for (int n = 0; n < 2; ++n) {
                int row = wc * 32 + n * 16 + fr;
                bfv[n] = *(const s16x8*)(&sB[row * BK + jp * 8]);
            }
#pragma unroll
            for (int m = 0; m < 4; ++m)
#pragma unroll
                for (int n = 0; n < 2; ++n)
                    acc[m][n] = __builtin_amdgcn_mfma_f32_16x16x32_bf16(
                        af[m], bfv[n], acc[m][n], 0, 0, 0);
        }
    }

    __syncthreads();   // done reading sA/sB; reuse LDS as sC
#pragma unroll
    for (int m = 0; m < 4; ++m)
#pragma unroll
        for (int n = 0; n < 2; ++n)
#pragma unroll
            for (int jj = 0; jj < 4; ++jj) {
                int r = wr * 64 + m * 16 + kg * 4 + jj;   // C/D: row=(lane>>4)*4+reg
                int c = wc * 32 + n * 16 + fr;            //      col=lane&15
                sC[r * 132 + c] = map16(bfbits(acc[m][n][jj]));
            }
    __syncthreads();
    if (bm == bn) {
        if (tid < 128) sC[tid * 132 + tid] = 0;   // diagonal sentinel (unique min)
        __syncthreads();
    }
#pragma unroll
    for (int it = 0; it < 4; ++it) {
        int idx = it * 512 + tid;                 // 0..2047 16B chunks
        int row = idx >> 4, col8 = (idx & 15) * 8;
        *(uint4*)(&Cp[(size_t)(bm + row) * NROW + bn + col8]) =
            *(const uint4*)(&sC[row * 132 + col8]);
    }
}

// ---------------- wave helpers ----------------
__device__ __forceinline__ u32 wave_sum_u32(u32 x) {
#pragma unroll
    for (int o = 32; o; o >>= 1) x += __shfl_down(x, o);
    return __shfl(x, 0);
}

// resolve rank `rem` within a 128-key sub-hist (packed u16 counts, 64 words)
__device__ __forceinline__ void resolve_slot(const u32* sub, int slot, u32 rem,
                                             int lane, u32* idxOut, u32* gtOut) {
    u32 word = sub[slot * 64 + lane];
    u32 c0 = word & 0xFFFFu, c1 = word >> 16;     // idx 2*lane, 2*lane+1
    u32 s0 = c0 + c1, suf = s0;
#pragma unroll
    for (int o = 1; o < 64; o <<= 1) {
        u32 v = __shfl_down(suf, o);
        if (lane + o < 64) suf += v;
    }
    u32 TexL = suf - s0;                  // counts in higher lanes
    u32 f = 0, pk = 0;
    u32 ab0 = TexL + c1;                  // keys above idx 2*lane
    if (rem >= ab0 && rem < ab0 + c0) { f = 1; pk = ((u32)(lane * 2) << 16) | ab0; }
    if (rem >= TexL && rem < TexL + c1) { f = 1; pk = ((u32)(lane * 2 + 1) << 16) | TexL; }
    u64 mm = __ballot(f != 0);
    pk = __shfl(pk, (int)(__ffsll((unsigned long long)mm) - 1));
    *idxOut = pk >> 16;
    *gtOut = pk & 0xFFFFu;
}

// full-row bisect via global re-sweeps (pathological fallback only)
__device__ u32 bisect_row(const uint4* rp, u32 rank, int lane) {
    u32 lo = 0, hi = 65535;
    while (lo < hi) {
        u32 mid = (lo + hi) >> 1;
        u32 pc = 0;
        for (int i = 0; i < 16; ++i) {
            uint4 v = rp[i * 64 + lane];
            pc += (u32)((v.x & 0xFFFFu) > mid) + (u32)((v.x >> 16) > mid)
                + (u32)((v.y & 0xFFFFu) > mid) + (u32)((v.y >> 16) > mid)
                + (u32)((v.z & 0xFFFFu) > mid) + (u32)((v.z >> 16) > mid)
                + (u32)((v.w & 0xFFFFu) > mid) + (u32)((v.w >> 16) > mid);
        }
        u32 c = wave_sum_u32(pc);
        if (c <= rank) hi = mid; else lo = mid + 1;
    }
    return lo;
}

// ---------------- rank select + LSE: 1 wave/row, 0 barriers, ONE sweep ----
// Speculative range R = values [8,64) (keys [0xC100,0xC280), 3 x 128-key
// slots). Numerics: with T=0.07, terms >2.8 below the window max vanish
// (<e^-40). If rank-819 in R, rank-4094 below R, and a >= 10.9 (all verified
// from exact counts), the dropped terms are < 1e-15 relative -> fp32-exact.
// Any violation -> exact full-row bisect fallback (never for benign data).
#define KLO 0xC100u     // key of value 8.0
#define KHI 0xC280u     // key of value 64.0
#define RSPAN 0x180u    // 384 keys, 3 slots
#define NSLOT 3

__global__ __launch_bounds__(128, 8) void rank_lse(const u16* __restrict__ Cp,
                                                   const float* __restrict__ fq,
                                                   const float* __restrict__ fk,
                                                   float* __restrict__ loss) {
    __shared__ u32 lds_s[2][NSLOT * 64];  // 1.5 KB/block; per-wave private
    const int t = threadIdx.x;
    const int w = t >> 6;
    const int lane = t & 63;
    const int row = blockIdx.x * 2 + w;

    u32* sub = lds_s[w];
    const uint4* rp = (const uint4*)(Cp + (size_t)row * NROW);

    // zero sub-hists (192 words)
    if (lane < 48) *(uint4*)&sub[lane * 4] = make_uint4(0, 0, 0, 0);

    // exact fp32 l_pos
    float lp;
    {
        float4 q4 = *(const float4*)(fq + (size_t)row * NDIM + lane * 4);
        float4 k4 = *(const float4*)(fk + (size_t)row * NDIM + lane * 4);
        float p = q4.x * k4.x + q4.y * k4.y + q4.z * k4.z + q4.w * k4.w;
#pragma unroll
        for (int o = 32; o; o >>= 1) p += __shfl_down(p, o);
        lp = __shfl(p, 0);
    }

    // ---- single sweep: count-above-R + sub-hist R keys ----
    u32 cntHi = 0;
#pragma unroll 4
    for (int i = 0; i < 16; ++i) {
        uint4 v = rp[i * 64 + lane];
        u32 vv[4] = { v.x, v.y, v.z, v.w };
#pragma unroll
        for (int q = 0; q < 4; ++q) {
#pragma unroll
            for (int hh = 0; hh < 2; ++hh) {
                u32 key = hh ? (vv[q] >> 16) : (vv[q] & 0xFFFFu);
                cntHi += (key >= KHI) ? 1u : 0u;
                u32 d = key - KLO;
                if (d < RSPAN)
                    atomicAdd(&sub[(d >> 7) * 64 + ((key >> 1) & 63u)],
                              (key & 1u) ? 0x10000u : 1u);
            }
        }
    }
    const u32 CH = wave_sum_u32(cntHi);

    // ---- slot totals (packed reduce) ----
    u32 T0, T1, T2;
    {
        u32 w0 = sub[lane], w1 = sub[64 + lane], w2 = sub[128 + lane];
        u32 m0 = (w0 & 0xFFFFu) + (w0 >> 16);
        u32 m1 = (w1 & 0xFFFFu) + (w1 >> 16);
        u32 m2 = (w2 & 0xFFFFu) + (w2 >> 16);
        u32 p01 = wave_sum_u32(m0 | (m1 << 16));
        T2 = wave_sum_u32(m2);
        T0 = p01 & 0xFFFFu; T1 = p01 >> 16;
    }
    const u32 NR = T0 + T1 + T2;

    bool fb = !((CH <= (u32)K_BOT) && ((u32)K_BOT < CH + NR))
            || ((u32)(K_TOP - 1) < CH + NR);

    u32 ua = 0, Ga = 0, Ea = 0;
    float a = 0.f;
    int sA = 0;
    if (!fb) {
        // locate slot of rank K_BOT (slot 2 = highest values)
        const u32 AT2 = CH, AT1 = CH + T2, AT0 = AT1 + T1;
        u32 ATA;
        if ((u32)K_BOT >= AT0)      { sA = 0; ATA = AT0; }
        else if ((u32)K_BOT >= AT1) { sA = 1; ATA = AT1; }
        else                        { sA = 2; ATA = AT2; }
        const u32 remA = (u32)K_BOT - ATA;
        u32 idxA, gtA;
        resolve_slot(sub, sA, remA, lane, &idxA, &gtA);
        ua = KLO + ((u32)sA << 7) + idxA;
        Ga = ATA + gtA;
        {
            u32 wv = sub[sA * 64 + (idxA >> 1)];
            Ea = (idxA & 1u) ? (wv >> 16) : (wv & 0xFFFFu);
        }
        a = unmap16(ua);
        if (!(a >= 10.9f)) fb = true;   // significance guard for dropped terms
    }

    if (!fb) {
        // ---- fast epilogue: everything from sub-hists ----
        const float m_ = fmaxf(fmaxf(lp, a), -10.0f) * INV_T;
        float sm = 0.f;
#pragma unroll
        for (int s = 0; s < NSLOT; ++s) {
            u32 wv = sub[s * 64 + lane];
            u32 c0 = wv & 0xFFFFu, c1 = wv >> 16;
            u32 k0 = KLO + ((u32)s << 7) + (u32)(lane * 2);
            u32 k1 = k0 | 1u;
            if (c0 && k0 < ua) sm += (float)c0 * __expf(unmap16(k0) * INV_T - m_);
            if (c1 && k1 < ua) sm += (float)c1 * __expf(unmap16(k1) * INV_T - m_);
        }
#pragma unroll
        for (int o = 32; o; o >>= 1) sm += __shfl_down(sm, o);
        if (lane == 0) {
            float expA = __expf(a * INV_T - m_);
            float tot = sm + (float)(int)(Ga + Ea - (u32)K_BOT) * expA;
            // B-side & sub-R terms provably < 1e-15 relative: omitted
            tot += __expf(lp * INV_T - m_)
                 + (float)N_UNSEL * __expf(-10.0f * INV_T - m_);
            loss[row] = m_ + __logf(tot) - lp * INV_T;
        }
    } else {
        // ---- exact fallback: full-row bisects + tie-exact sweep ----
        u32 fua = bisect_row(rp, (u32)K_BOT, lane);
        u32 fub = bisect_row(rp, (u32)(K_TOP - 1), lane);
        float fa = unmap16(fua);
        const float m_ = fmaxf(fmaxf(lp, fa), -10.0f) * INV_T;
        u32 cga = 0, cea = 0, cgb = 0;
        float sm = 0.f;
        for (int i = 0; i < 16; ++i) {
            uint4 v = rp[i * 64 + lane];
            u32 vv[4] = { v.x, v.y, v.z, v.w };
#pragma unroll
            for (int q = 0; q < 4; ++q) {
#pragma unroll
                for (int hh = 0; hh < 2; ++hh) {
                    u32 u = hh ? (vv[q] >> 16) : (vv[q] & 0xFFFFu);
                    cga += (u > fua); cea += (u == fua); cgb += (u > fub);
                    if (u > fub && u < fua)
                        sm += __expf(unmap16(u) * INV_T - m_);
                }
            }
        }
        u32 fGa = wave_sum_u32(cga), fEa = wave_sum_u32(cea), fGb = wave_sum_u32(cgb);
#pragma unroll
        for (int o = 32; o; o >>= 1) sm += __shfl_down(sm, o);
        if (lane == 0) {
            float bv = unmap16(fub);
            float expA = __expf(fa * INV_T - m_);
            float tot;
            if (fua == fub) {
                tot = (float)N_SEL * expA;
            } else {
                float expB = __expf(bv * INV_T - m_);
                tot = sm + (float)(int)(fGa + fEa - (u32)K_BOT) * expA
                         + (float)(int)((u32)K_TOP - fGb) * expB;
            }
            tot += __expf(lp * INV_T - m_)
                 + (float)N_UNSEL * __expf(-10.0f * INV_T - m_);
            loss[row] = m_ + __logf(tot) - lp * INV_T;
        }
    }
}

// ---------------- host ----------------
extern "C" void kernel_launch(void* const* d_in, const int* in_sizes, int n_in,
                              void* d_out, int out_size, void* d_ws, size_t ws_size,
                              hipStream_t stream) {
    const float* fq = (const float*)d_in[0];
    const float* fk = (const float*)d_in[1];
    float* out = (float*)d_out;

    char* ws = (char*)d_ws;
    u16* keys = (u16*)ws;                                  // 128 MiB
    u16* qb = (u16*)(ws + (size_t)NROW * NROW * 2);        // 4 MiB
    u16* kb = qb + (size_t)NROW * NDIM;                    // 4 MiB

    cvt_bf16<<<4096, 256, 0, stream>>>(fq, fk, qb, kb);
    gemm_keys<<<dim3(NROW / 128, NROW / 128), 512, 0, stream>>>(qb, kb, keys);
    rank_lse<<<NROW / 2, 128, 0, stream>>>(keys, fq, fk, out);
}